// Round 1
// baseline (292.836 us; speedup 1.0000x reference)
//
#include <hip/hip_runtime.h>
#include <hip/hip_bf16.h>
#include <stdint.h>

// ---- constants ----
// B=8, Cin=128, H=W=160, Ce=64, NH=4, HC=16, N=80, Cg=512, Co=128
// Padded bf16 NHWC x: [8][162][176][128], interior (h,w) -> (h+1, w+8)

typedef __attribute__((ext_vector_type(8))) short short8;
typedef __attribute__((ext_vector_type(4))) float f32x4;

__device__ __forceinline__ unsigned short f2bf(float f) {
  unsigned int u = __float_as_uint(f);
  u += 0x7fff + ((u >> 16) & 1);   // round-to-nearest-even
  return (unsigned short)(u >> 16);
}

__device__ __forceinline__ short8 zero8() {
  short8 z = {0,0,0,0,0,0,0,0};
  return z;
}

// ------------------------------------------------------------------
// P0: x fp32 NCHW -> bf16 NHWC padded [8][162][176][128], zero borders
// ------------------------------------------------------------------
__global__ __launch_bounds__(192) void k_prep_x(const float* __restrict__ x,
                                                unsigned short* __restrict__ P) {
  int b = blockIdx.x / 162, hp = blockIdx.x % 162;
  int wp = threadIdx.x;
  if (wp >= 176) return;
  size_t obase = (((size_t)b * 162 + hp) * 176 + wp) * 128;
  bool interior = (hp >= 1) && (hp <= 160) && (wp >= 8) && (wp < 168);
  if (!interior) {
    for (int cc = 0; cc < 16; ++cc) *(short8*)(&P[obase + cc * 8]) = zero8();
    return;
  }
  int h = hp - 1, w = wp - 8;
  const float* xb = x + (size_t)b * 128 * 25600 + h * 160 + w;
  for (int cc = 0; cc < 16; ++cc) {
    short8 v;
#pragma unroll
    for (int j = 0; j < 8; ++j) {
      float f = xb[(size_t)(cc * 8 + j) * 25600];
      v[j] = (short)f2bf(f);
    }
    *(short8*)(&P[obase + cc * 8]) = v;
  }
}

// ------------------------------------------------------------------
// P1: weight conversions + BN2 folding
//   W1t [64][128] bf16 ; Wpt [9][128 co][128 ci] bf16 ; s2,t2 [128] f32
// ------------------------------------------------------------------
__global__ __launch_bounds__(256) void k_prep_misc(
    const float* __restrict__ w_embed, const float* __restrict__ w_proj,
    const float* __restrict__ g2, const float* __restrict__ b2,
    const float* __restrict__ rm2, const float* __restrict__ rv2,
    unsigned short* __restrict__ W1t, unsigned short* __restrict__ Wpt,
    float* __restrict__ s2, float* __restrict__ t2) {
  int idx = blockIdx.x * 256 + threadIdx.x;
  if (idx < 8192) { W1t[idx] = f2bf(w_embed[idx]); return; }
  idx -= 8192;
  if (idx < 147456) {
    int tap = idx >> 14, rem = idx & 16383;
    int co = rem >> 7, ci = rem & 127;
    Wpt[idx] = f2bf(w_proj[(co * 128 + ci) * 9 + tap]);
    return;
  }
  idx -= 147456;
  if (idx < 128) {
    float s = g2[idx] * rsqrtf(rv2[idx] + 1e-3f);
    s2[idx] = s;
    t2[idx] = b2[idx] - rm2[idx] * s;
  }
}

// ------------------------------------------------------------------
// P2: guide GEMM + BN1 folding
//   Gpad [8][4][80][32] bf16  (k<16: g_raw*s1 ; k>=16: 0)
//   Cst  [8][4][80] f32       (dot(g_raw, t1) per head)
// ------------------------------------------------------------------
__global__ __launch_bounds__(64) void k_guide(
    const float* __restrict__ guide, const float* __restrict__ Wg,
    const float* __restrict__ bg, const float* __restrict__ g1,
    const float* __restrict__ b1, const float* __restrict__ rm1,
    const float* __restrict__ rv1, unsigned short* __restrict__ Gpad,
    float* __restrict__ Cst) {
  int b = blockIdx.x / 80, n = blockIdx.x % 80;
  __shared__ float gs[512];
  const float* gr = guide + ((size_t)b * 80 + n) * 512;
  for (int i = threadIdx.x; i < 512; i += 64) gs[i] = gr[i];
  __syncthreads();
  int ce = threadIdx.x;
  const float* wr = Wg + (size_t)ce * 512;
  float acc = 0.f;
  for (int k = 0; k < 512; k += 4)
    acc += gs[k] * wr[k] + gs[k + 1] * wr[k + 1] + gs[k + 2] * wr[k + 2] +
           gs[k + 3] * wr[k + 3];
  float raw = acc + bg[ce];
  float s1 = g1[ce] * rsqrtf(rv1[ce] + 1e-3f);
  float t1 = b1[ce] - rm1[ce] * s1;
  int head = ce >> 4, c = ce & 15;
  size_t gp = (((size_t)b * 4 + head) * 80 + n) * 32;
  Gpad[gp + c] = f2bf(raw * s1);
  Gpad[gp + 16 + c] = 0;
  float cp = raw * t1;
  cp += __shfl_xor(cp, 1);
  cp += __shfl_xor(cp, 2);
  cp += __shfl_xor(cp, 4);
  cp += __shfl_xor(cp, 8);
  if (c == 0) Cst[((size_t)b * 4 + head) * 80 + n] = cp;
}

// ------------------------------------------------------------------
// K2: fused embed 1x1 conv (MFMA) + per-head scores (MFMA, K padded
//     16->32) + max over 80 guides + sigmoid -> aw [8][4][160][160]
// Block: 256 px flat (100 blocks/image), 256 thr (4 waves x 64 px)
// ------------------------------------------------------------------
__global__ __launch_bounds__(256) void k_attn(
    const unsigned short* __restrict__ P, const unsigned short* __restrict__ W1t,
    const unsigned short* __restrict__ Gpad, const float* __restrict__ Cst,
    const float* __restrict__ attn_bias, float* __restrict__ aw) {
  __shared__ unsigned short E[32768];  // 64 KB: [256 px][16 slots][8], XOR-swizzled
  int b = blockIdx.x / 100;
  int px0 = (blockIdx.x % 100) * 256;
  int tid = threadIdx.x, lane = tid & 63, wv = tid >> 6;
  int l15 = lane & 15, l4 = lane >> 4;

  // zero E (padded-K slices must be 0; zero everything, swizzle-agnostic)
  for (int i = 0; i < 16; ++i) *(short8*)(&E[tid * 128 + i * 8]) = zero8();
  __syncthreads();

  // stage 1: E_raw[px][ce] = sum_cin X[px][cin] * W1[ce][cin]
  f32x4 acc[4][4];
#pragma unroll
  for (int mt = 0; mt < 4; ++mt)
#pragma unroll
    for (int nt = 0; nt < 4; ++nt) acc[mt][nt] = (f32x4){0.f, 0.f, 0.f, 0.f};

  const unsigned short* Ab[4];
#pragma unroll
  for (int mt = 0; mt < 4; ++mt) {
    int px = px0 + wv * 64 + mt * 16 + l15;
    int h = px / 160, w = px - h * 160;
    Ab[mt] = P + (((size_t)b * 162 + h + 1) * 176 + (w + 8)) * 128 + l4 * 8;
  }
#pragma unroll
  for (int kc = 0; kc < 4; ++kc) {
    short8 A[4], Bf[4];
#pragma unroll
    for (int mt = 0; mt < 4; ++mt) A[mt] = *(const short8*)(Ab[mt] + kc * 32);
#pragma unroll
    for (int nt = 0; nt < 4; ++nt)
      Bf[nt] = *(const short8*)(W1t + (nt * 16 + l15) * 128 + kc * 32 + l4 * 8);
#pragma unroll
    for (int mt = 0; mt < 4; ++mt)
#pragma unroll
      for (int nt = 0; nt < 4; ++nt)
        acc[mt][nt] = __builtin_amdgcn_mfma_f32_16x16x32_bf16(A[mt], Bf[nt],
                                                              acc[mt][nt], 0, 0, 0);
  }
  // write E to LDS as bf16, layout [px][head][k(32)], slot-swizzled by px&7
#pragma unroll
  for (int mt = 0; mt < 4; ++mt)
#pragma unroll
    for (int nt = 0; nt < 4; ++nt)
#pragma unroll
      for (int r = 0; r < 4; ++r) {
        int pxl = wv * 64 + mt * 16 + l4 * 4 + r;
        int slot = (nt * 4 + (l15 >> 3)) ^ (pxl & 7);
        E[pxl * 128 + slot * 8 + (l15 & 7)] = f2bf(acc[mt][nt][r]);
      }
  __syncthreads();

  // stage 2: per head, S[n][px] = Gpad @ E_head ; max over n; sigmoid
  const f32x4 zf = (f32x4){0.f, 0.f, 0.f, 0.f};
#pragma unroll
  for (int head = 0; head < 4; ++head) {
    short8 Ga[5];
    f32x4 cst[5];
#pragma unroll
    for (int m5 = 0; m5 < 5; ++m5) {
      Ga[m5] = *(const short8*)(Gpad + (((size_t)b * 4 + head) * 80 + m5 * 16 + l15) * 32 + l4 * 8);
      cst[m5] = *(const f32x4*)(Cst + ((size_t)b * 4 + head) * 80 + m5 * 16 + l4 * 4);
    }
    float bias = attn_bias[head];
#pragma unroll
    for (int nt = 0; nt < 4; ++nt) {
      int pxl = wv * 64 + nt * 16 + l15;
      int slot = (head * 4 + l4) ^ (pxl & 7);
      short8 Bf = *(const short8*)(&E[pxl * 128 + slot * 8]);
      float mx = -3.0e38f;
#pragma unroll
      for (int m5 = 0; m5 < 5; ++m5) {
        f32x4 s = __builtin_amdgcn_mfma_f32_16x16x32_bf16(Ga[m5], Bf, zf, 0, 0, 0);
#pragma unroll
        for (int r = 0; r < 4; ++r) mx = fmaxf(mx, s[r] + cst[m5][r]);
      }
      mx = fmaxf(mx, __shfl_xor(mx, 16));
      mx = fmaxf(mx, __shfl_xor(mx, 32));
      if (lane < 16) {
        float v = 1.f / (1.f + __expf(-(mx * 0.25f + bias)));
        aw[((size_t)b * 4 + head) * 25600 + px0 + wv * 64 + nt * 16 + lane] = v;
      }
    }
  }
}

// ------------------------------------------------------------------
// K3: 3x3 conv as 9 shifted 1x1 GEMMs + BN + aw gate
// Block tile: [4h x 32w px] x [128 co]; 4 waves = 2M x 2N (64px x 64co each)
// LDS: x tile [6 rows][48 w][128 cin] bf16 = 73728 B, staged once, XOR-swizzled
// ------------------------------------------------------------------
__global__ __launch_bounds__(256) void k_conv(
    const unsigned short* __restrict__ P, const unsigned short* __restrict__ Wpt,
    const float* __restrict__ s2, const float* __restrict__ t2,
    const float* __restrict__ aw, float* __restrict__ out) {
  __shared__ unsigned short X[36864];
  int blk = blockIdx.x;
  int b = blk / 200, r2 = blk % 200;
  int ht = r2 / 5, wt = r2 % 5;
  int h0 = ht * 4, w0 = wt * 32;
  int tid = threadIdx.x, lane = tid & 63, wv = tid >> 6;
  int l15 = lane & 15, l4 = lane >> 4;

  // stage: 4608 16B chunks; chunk (row,w2,c16) -> LDS slot with c16 ^= w2&7
  for (int i = 0; i < 18; ++i) {
    int k = i * 256 + tid;
    int row = k / 768;
    int rem = k - row * 768;
    int w2 = rem >> 4, c16 = rem & 15;
    short8 v = *(const short8*)(P + ((((size_t)b * 162 + h0 + row) * 176 + (w0 + w2)) * 128 + c16 * 8));
    *(short8*)(&X[(row * 768 + w2 * 16 + (c16 ^ (w2 & 7))) * 8]) = v;
  }
  __syncthreads();

  int mh = wv >> 1, nh = wv & 1;
  f32x4 acc[4][4];
#pragma unroll
  for (int j = 0; j < 4; ++j)
#pragma unroll
    for (int nt = 0; nt < 4; ++nt) acc[j][nt] = (f32x4){0.f, 0.f, 0.f, 0.f};

  int bco[4];
#pragma unroll
  for (int nt = 0; nt < 4; ++nt) bco[nt] = (nh * 64 + nt * 16 + l15) * 128 + l4 * 8;

  for (int tap = 0; tap < 9; ++tap) {
    int ky = tap / 3, kx = tap - ky * 3;
    int rb[4], wj[4];
#pragma unroll
    for (int j = 0; j < 4; ++j) {
      int hl = mh * 2 + (j >> 1), wh = j & 1;
      rb[j] = hl + ky;                    // LDS row
      wj[j] = wh * 16 + l15 + 7 + kx;     // LDS w'
    }
#pragma unroll
    for (int kc = 0; kc < 4; ++kc) {
      short8 A[4], Bf[4];
#pragma unroll
      for (int j = 0; j < 4; ++j)
        A[j] = *(const short8*)(&X[((rb[j] * 48 + wj[j]) * 16 + ((kc * 4 + l4) ^ (wj[j] & 7))) * 8]);
#pragma unroll
      for (int nt = 0; nt < 4; ++nt)
        Bf[nt] = *(const short8*)(Wpt + tap * 16384 + kc * 32 + bco[nt]);
#pragma unroll
      for (int j = 0; j < 4; ++j)
#pragma unroll
        for (int nt = 0; nt < 4; ++nt)
          acc[j][nt] = __builtin_amdgcn_mfma_f32_16x16x32_bf16(A[j], Bf[nt],
                                                               acc[j][nt], 0, 0, 0);
    }
  }

  // epilogue: BN + gate + store
  float s2v[4], t2v[4];
#pragma unroll
  for (int nt = 0; nt < 4; ++nt) {
    int co = nh * 64 + nt * 16 + l15;
    s2v[nt] = s2[co];
    t2v[nt] = t2[co];
  }
#pragma unroll
  for (int j = 0; j < 4; ++j) {
    int hl = mh * 2 + (j >> 1), wh = j & 1;
    int h = h0 + hl, wbase = w0 + wh * 16 + l4 * 4;
    f32x4 aw0 = *(const f32x4*)(aw + (size_t)(b * 4 + nh * 2) * 25600 + h * 160 + wbase);
    f32x4 aw1 = *(const f32x4*)(aw + (size_t)(b * 4 + nh * 2 + 1) * 25600 + h * 160 + wbase);
#pragma unroll
    for (int nt = 0; nt < 4; ++nt) {
      int co = nh * 64 + nt * 16 + l15;
      f32x4 g = (nt < 2) ? aw0 : aw1;
      f32x4 o;
#pragma unroll
      for (int r = 0; r < 4; ++r) o[r] = (acc[j][nt][r] * s2v[nt] + t2v[nt]) * g[r];
      *(f32x4*)(out + (size_t)(b * 128 + co) * 25600 + h * 160 + wbase) = o;
    }
  }
}

// ------------------------------------------------------------------
extern "C" void kernel_launch(void* const* d_in, const int* in_sizes, int n_in,
                              void* d_out, int out_size, void* d_ws, size_t ws_size,
                              hipStream_t stream) {
  (void)in_sizes; (void)n_in; (void)out_size; (void)ws_size;
  const float* x         = (const float*)d_in[0];
  const float* guide     = (const float*)d_in[1];
  const float* w_embed   = (const float*)d_in[2];
  const float* g1        = (const float*)d_in[3];
  const float* b1        = (const float*)d_in[4];
  const float* rm1       = (const float*)d_in[5];
  const float* rv1       = (const float*)d_in[6];
  const float* Wg        = (const float*)d_in[7];
  const float* bg        = (const float*)d_in[8];
  const float* attn_bias = (const float*)d_in[9];
  const float* w_proj    = (const float*)d_in[10];
  const float* g2        = (const float*)d_in[11];
  const float* b2        = (const float*)d_in[12];
  const float* rm2       = (const float*)d_in[13];
  const float* rv2       = (const float*)d_in[14];
  float* out = (float*)d_out;

  char* ws = (char*)d_ws;
  unsigned short* P    = (unsigned short*)(ws);               // 58,392,576 B
  unsigned short* W1t  = (unsigned short*)(ws + 58392576);    //     16,384 B
  unsigned short* Wpt  = (unsigned short*)(ws + 58408960);    //    294,912 B
  unsigned short* Gpad = (unsigned short*)(ws + 58703872);    //    163,840 B
  float* Cst           = (float*)(ws + 58867712);             //     10,240 B
  float* s2            = (float*)(ws + 58877952);             //        512 B
  float* t2            = (float*)(ws + 58878464);             //        512 B
  float* aw            = (float*)(ws + 58878976);             //  3,276,800 B
  // total ws usage: 62,155,776 B

  k_prep_x<<<8 * 162, 192, 0, stream>>>(x, P);
  k_prep_misc<<<609, 256, 0, stream>>>(w_embed, w_proj, g2, b2, rm2, rv2, W1t, Wpt, s2, t2);
  k_guide<<<640, 64, 0, stream>>>(guide, Wg, bg, g1, b1, rm1, rv1, Gpad, Cst);
  k_attn<<<800, 256, 0, stream>>>(P, W1t, Gpad, Cst, attn_bias, aw);
  k_conv<<<1600, 256, 0, stream>>>(P, Wpt, s2, t2, aw, out);
}